// Round 1
// baseline (308.741 us; speedup 1.0000x reference)
//
#include <hip/hip_runtime.h>

// ---------------------------------------------------------------------------
// ContrastiveLoss: loss = mean_i [ 0.5*(logsumexp_row_i + logsumexp_col_i) - diag_i ]
// over logits = normalize(img) @ normalize(txt)^T / 0.07, N=8192, D=1024.
// |logit| <= 1/0.07 = 14.29 -> exp() never overflows fp32; no max subtraction
// needed. Pipeline: normalize->bf16, tiled MFMA GEMM with fused exp + atomic
// row/col sums + diag capture, then a tiny log/mean reduction.
// ---------------------------------------------------------------------------

#define BM 128
#define BN 128
#define BK 32

typedef __bf16 bf16x8 __attribute__((ext_vector_type(8)));
typedef float  floatx4 __attribute__((ext_vector_type(4)));

__device__ __forceinline__ unsigned short f2bf(float f) {
    unsigned int u = __float_as_uint(f);
    u += 0x7fffu + ((u >> 16) & 1u);   // round-to-nearest-even
    return (unsigned short)(u >> 16);
}

__device__ __forceinline__ void gload_lds16(const unsigned short* g, unsigned short* lds) {
    __builtin_amdgcn_global_load_lds(
        (const __attribute__((address_space(1))) void*)g,
        (__attribute__((address_space(3))) void*)lds,
        16, 0, 0);
}

// ---- Kernel 1: row L2-normalize (clamp at eps) and cast fp32 -> bf16 -------
__global__ __launch_bounds__(256)
void normalize_bf16(const float* __restrict__ in, unsigned short* __restrict__ out, int D) {
    const int row = blockIdx.x;
    const int t = threadIdx.x;
    const float4 v = ((const float4*)(in + (size_t)row * D))[t];
    float ss = v.x * v.x + v.y * v.y + v.z * v.z + v.w * v.w;
    #pragma unroll
    for (int o = 1; o < 64; o <<= 1) ss += __shfl_xor(ss, o);
    __shared__ float wss[4];
    if ((t & 63) == 0) wss[t >> 6] = ss;
    __syncthreads();
    const float tot = wss[0] + wss[1] + wss[2] + wss[3];
    const float inv = 1.0f / fmaxf(sqrtf(tot), 1e-8f);
    ushort4 o4;
    o4.x = f2bf(v.x * inv);
    o4.y = f2bf(v.y * inv);
    o4.z = f2bf(v.z * inv);
    o4.w = f2bf(v.w * inv);
    *(ushort4*)(out + (size_t)row * D + t * 4) = o4;
}

// ---- Kernel 2: 128x128-tile NT GEMM + fused exp / row-col sums / diag ------
__global__ __launch_bounds__(256)
void gemm_exp_kernel(const unsigned short* __restrict__ A,   // img_n [N][K] bf16
                     const unsigned short* __restrict__ B,   // txt_n [N][K] bf16
                     float* __restrict__ rowsum, float* __restrict__ colsum,
                     float* __restrict__ diag, int K, float scale) {
    __shared__ unsigned short As[BM * BK];   // 8 KB
    __shared__ unsigned short Bs[BN * BK];   // 8 KB

    const int bm = blockIdx.x, bn = blockIdx.y;
    const int tid = threadIdx.x;
    const int lane = tid & 63;
    const int wave = tid >> 6;
    const int quad = lane >> 4;
    const int lanelo = lane & 15;
    const int wrow = (wave >> 1) * 64;   // wave quadrant within 128x128
    const int wcol = (wave & 1) * 64;

    floatx4 acc[4][4] = {};

    // staging: 512 16B-chunks per tile; wave w covers chunks [w*128, w*128+128)
    const int c0 = wave * 128 + lane;
    const int c1 = c0 + 64;
    const int rA0 = c0 >> 2, kb0 = (c0 & 3) * 8;
    const int rA1 = c1 >> 2, kb1 = (c1 & 3) * 8;

    const size_t abase = (size_t)bm * BM * K;
    const size_t bbase = (size_t)bn * BN * K;

    for (int k0 = 0; k0 < K; k0 += BK) {
        gload_lds16(A + abase + (size_t)rA0 * K + k0 + kb0, As + c0 * 8);
        gload_lds16(A + abase + (size_t)rA1 * K + k0 + kb1, As + c1 * 8);
        gload_lds16(B + bbase + (size_t)rA0 * K + k0 + kb0, Bs + c0 * 8);
        gload_lds16(B + bbase + (size_t)rA1 * K + k0 + kb1, Bs + c1 * 8);
        __syncthreads();

        bf16x8 af[4], bg[4];
        #pragma unroll
        for (int t = 0; t < 4; ++t)
            af[t] = *(const bf16x8*)(As + (wrow + t * 16 + lanelo) * BK + quad * 8);
        #pragma unroll
        for (int t = 0; t < 4; ++t)
            bg[t] = *(const bf16x8*)(Bs + (wcol + t * 16 + lanelo) * BK + quad * 8);

        #pragma unroll
        for (int tm = 0; tm < 4; ++tm)
            #pragma unroll
            for (int tn = 0; tn < 4; ++tn)
                acc[tm][tn] = __builtin_amdgcn_mfma_f32_16x16x32_bf16(
                    af[tm], bg[tn], acc[tm][tn], 0, 0, 0);
        __syncthreads();
    }

    // ---- epilogue: scale, capture diag, exp in place ----
    const int growb = bm * BM + wrow;
    const int gcolb = bn * BN + wcol;

    #pragma unroll
    for (int tm = 0; tm < 4; ++tm)
        #pragma unroll
        for (int tn = 0; tn < 4; ++tn)
            #pragma unroll
            for (int r = 0; r < 4; ++r) {
                const float l = acc[tm][tn][r] * scale;
                const int grow = growb + tm * 16 + quad * 4 + r;
                const int gcol = gcolb + tn * 16 + lanelo;
                if (grow == gcol) diag[grow] = l;
                acc[tm][tn][r] = __expf(l);
            }

    // ---- row sums: reduce over the 16 lanes sharing a row, then atomicAdd ----
    #pragma unroll
    for (int tm = 0; tm < 4; ++tm) {
        floatx4 rs = acc[tm][0] + acc[tm][1] + acc[tm][2] + acc[tm][3];
        #pragma unroll
        for (int r = 0; r < 4; ++r) {
            float v = rs[r];
            v += __shfl_xor(v, 1);
            v += __shfl_xor(v, 2);
            v += __shfl_xor(v, 4);
            v += __shfl_xor(v, 8);
            if (lanelo == 0)
                atomicAdd(&rowsum[growb + tm * 16 + quad * 4 + r], v);
        }
    }

    // ---- col sums: reduce over quads (xor 16, 32), then atomicAdd ----
    #pragma unroll
    for (int tn = 0; tn < 4; ++tn) {
        float cs = 0.f;
        #pragma unroll
        for (int tm = 0; tm < 4; ++tm)
            cs += acc[tm][tn][0] + acc[tm][tn][1] + acc[tm][tn][2] + acc[tm][tn][3];
        cs += __shfl_xor(cs, 16);
        cs += __shfl_xor(cs, 32);
        if (quad == 0)
            atomicAdd(&colsum[gcolb + tn * 16 + lanelo], cs);
    }
}

// ---- Kernel 3: loss = mean( 0.5*(log(rowsum)+log(colsum)) - diag ) ---------
__global__ __launch_bounds__(256)
void final_reduce(const float* __restrict__ rowsum, const float* __restrict__ colsum,
                  const float* __restrict__ diag, float* __restrict__ out, int n) {
    const int t = threadIdx.x;
    float acc = 0.f;
    for (int i = t; i < n; i += 256)
        acc += 0.5f * (logf(rowsum[i]) + logf(colsum[i])) - diag[i];
    #pragma unroll
    for (int o = 1; o < 64; o <<= 1) acc += __shfl_xor(acc, o);
    __shared__ float ws[4];
    if ((t & 63) == 0) ws[t >> 6] = acc;
    __syncthreads();
    if (t == 0) out[0] = (ws[0] + ws[1] + ws[2] + ws[3]) / (float)n;
}

extern "C" void kernel_launch(void* const* d_in, const int* in_sizes, int n_in,
                              void* d_out, int out_size, void* d_ws, size_t ws_size,
                              hipStream_t stream) {
    const float* img = (const float*)d_in[0];
    const float* txt = (const float*)d_in[1];
    float* out = (float*)d_out;

    const int D = 1024;
    const int N = in_sizes[0] / D;   // 8192

    unsigned short* imgn = (unsigned short*)d_ws;
    unsigned short* txtn = imgn + (size_t)N * D;
    float* rowsum = (float*)(txtn + (size_t)N * D);
    float* colsum = rowsum + N;
    float* diag = colsum + N;

    normalize_bf16<<<N, 256, 0, stream>>>(img, imgn, D);
    normalize_bf16<<<N, 256, 0, stream>>>(txt, txtn, D);
    hipMemsetAsync(rowsum, 0, 2 * (size_t)N * sizeof(float), stream);

    dim3 grid(N / BM, N / BN);
    gemm_exp_kernel<<<grid, 256, 0, stream>>>(imgn, txtn, rowsum, colsum, diag,
                                              D, 1.0f / 0.07f);
    final_reduce<<<1, 256, 0, stream>>>(rowsum, colsum, diag, out, N);
}